// Round 1
// baseline (6732.037 us; speedup 1.0000x reference)
//
#include <hip/hip_runtime.h>

#define FDIM 16
#define TDIM 16
#define MDIM 10
#define KDIM 17
#define NCG 5
#define NSINK 25
#define EPSV 0.05f

// DPP move within a 16-lane row (VALU, avoids the shared LDS unit).
template <int CTRL>
__device__ __forceinline__ float dppf(float x) {
  return __int_as_float(__builtin_amdgcn_update_dpp(
      0, __float_as_int(x), CTRL, 0xF, 0xF, true));
}
// All-reduce sum over the 16-lane row via row_ror:1,2,4,8.
__device__ __forceinline__ float sum16(float v) {
  v += dppf<0x121>(v);
  v += dppf<0x122>(v);
  v += dppf<0x124>(v);
  v += dppf<0x128>(v);
  return v;
}
__device__ __forceinline__ float max16(float v) {
  v = fmaxf(v, dppf<0x121>(v));
  v = fmaxf(v, dppf<0x122>(v));
  v = fmaxf(v, dppf<0x124>(v));
  v = fmaxf(v, dppf<0x128>(v));
  return v;
}

__global__ __launch_bounds__(256) void fgw_kernel(
    const float* __restrict__ x,        // [N,F]
    const int* __restrict__ nbrs,       // [N,K]
    const float* __restrict__ tmpl,     // [T,M,M]
    const float* __restrict__ tfeat,    // [T,M,F]
    const float* __restrict__ alpha,    // [1]
    float* __restrict__ out)            // [N,T]
{
  const int n = blockIdx.x;
  const int tid = threadIdx.x;
  const int t = tid >> 4;          // template id: 16 groups per block
  const int lane = tid & 15;       // column m within group
  const bool act = lane < MDIM;
  const int m = act ? lane : 0;

  __shared__ int sIdx[KDIM];
  __shared__ float sF1[KDIM][FDIM];

  if (tid < KDIM) sIdx[tid] = nbrs[n * KDIM + tid];
  __syncthreads();
  for (int i = tid; i < KDIM * FDIM; i += 256)
    sF1[i >> 4][i & 15] = x[sIdx[i >> 4] * FDIM + (i & 15)];
  __syncthreads();

  const float a  = alpha[0];
  const float w0 = 1.f - a;       // weight on Mcost in G
  const float w2 = 2.f * a;       // weight on tens in G

  // per-lane template data (column m of template t)
  float c2row[MDIM], f2[FDIM];
#pragma unroll
  for (int j = 0; j < MDIM; ++j)
    c2row[j] = act ? tmpl[(t * MDIM + m) * MDIM + j] : 0.f;
#pragma unroll
  for (int f = 0; f < FDIM; ++f)
    f2[f] = act ? tfeat[(t * MDIM + m) * FDIM + f] : 0.f;

  float n2 = 0.f, c2c = 0.f;
#pragma unroll
  for (int f = 0; f < FDIM; ++f) n2 += f2[f] * f2[f];
#pragma unroll
  for (int j = 0; j < MDIM; ++j) c2c += c2row[j] * c2row[j];
  c2c *= 0.1f;  // (C2*C2) @ h2, h2 = 1/10

  // Mcost column m: ||F1_k||^2 + ||F2_m||^2 - 2 F1_k . F2_m
  float Mc[KDIM];
#pragma unroll
  for (int k = 0; k < KDIM; ++k) {
    float dot = 0.f, n1 = 0.f;
#pragma unroll
    for (int f = 0; f < FDIM; ++f) {
      float v = sF1[k][f];
      dot += v * f2[f];
      n1 += v * v;
    }
    Mc[k] = n1 + n2 - 2.f * dot;
  }

  const float c1_0 = 16.f / 17.f;   // (C1 @ h1)[0]
  const float c1_r = 1.f / 17.f;    // (C1 @ h1)[k>=1]
  const float logh1 = -2.833213344f;  // log(1/17)
  const float logh2 = -2.302585093f;  // log(1/10)

  float Tc[KDIM];
#pragma unroll
  for (int k = 0; k < KDIM; ++k) Tc[k] = act ? (1.f / 170.f) : 0.f;

  float logK[KDIM], phi[KDIM];

#pragma unroll 1
  for (int it = 0; it < NCG; ++it) {
    // ---- tens(Tc): star C1 collapses C1*Tc*C2^T to two scalars per column
    float u = 0.f;
#pragma unroll
    for (int k = 1; k < KDIM; ++k) u += Tc[k];
    float t0 = Tc[0];
    float d0 = 0.f, d1 = 0.f;
#pragma unroll
    for (int j = 0; j < MDIM; ++j) {
      d0 += __shfl(u, j, 16) * c2row[j];
      d1 += __shfl(t0, j, 16) * c2row[j];
    }
    const float tens0 = c1_0 + c2c - 2.f * d0;  // row k = 0
    const float tens1 = c1_r + c2c - 2.f * d1;  // rows k >= 1

    // ---- G, scale
    float mabs = 0.f;
#pragma unroll
    for (int k = 0; k < KDIM; ++k) {
      float g = w0 * Mc[k] + w2 * (k == 0 ? tens0 : tens1);
      logK[k] = g;
      mabs = fmaxf(mabs, fabsf(g));
    }
    if (!act) mabs = 0.f;
    mabs = max16(mabs);
    const float nsc = -1.f / ((mabs + 1e-12f) * EPSV);
#pragma unroll
    for (int k = 0; k < KDIM; ++k)
      logK[k] = act ? logK[k] * nsc : -__builtin_inff();

    // ---- log-domain Sinkhorn, phi = f/eps, psi = g/eps
#pragma unroll
    for (int k = 0; k < KDIM; ++k) phi[k] = 0.f;
    float psi = 0.f;

#pragma unroll 1
    for (int s = 0; s < NSINK; ++s) {
      // f-update: phi_k = logh1 - lse_m(logK[k,m] + psi_m)
      float tv[KDIM];
      float gmax = -__builtin_inff();
#pragma unroll
      for (int k = 0; k < KDIM; ++k) {
        tv[k] = logK[k] + psi;            // inactive: -inf
        gmax = fmaxf(gmax, tv[k]);
      }
      gmax = max16(gmax);  // global max is safe: row range <= 2/eps = 40
#pragma unroll
      for (int k = 0; k < KDIM; ++k) {
        float ssum = sum16(__expf(tv[k] - gmax));
        phi[k] = logh1 - (gmax + __logf(ssum));
      }
      // g-update: psi_m = logh2 - lse_k(logK[k,m] + phi_k)   (lane-local)
      float mx = -__builtin_inff(), s2 = 0.f;
#pragma unroll
      for (int k = 0; k < KDIM; ++k) {
        tv[k] = logK[k] + phi[k];
        mx = fmaxf(mx, tv[k]);
      }
#pragma unroll
      for (int k = 0; k < KDIM; ++k) s2 += __expf(tv[k] - mx);
      psi = logh2 - (mx + __logf(s2));
      if (!act) psi = 0.f;  // kill NaN from the dead column
    }

    // ---- CG step: Tc += gamma * (S - Tc), S = exp(logK + phi + psi)
    const float gamma = 2.f / (float)(it + 2);
#pragma unroll
    for (int k = 0; k < KDIM; ++k) {
      float S = __expf(logK[k] + phi[k] + psi);  // inactive: exp(-inf) = 0
      Tc[k] += gamma * (S - Tc[k]);
    }
  }

  // ---- final tens with converged Tc, then fgw = sum Tc*( (1-a)Mc + a*tens )
  float u = 0.f;
#pragma unroll
  for (int k = 1; k < KDIM; ++k) u += Tc[k];
  float t0 = Tc[0];
  float d0 = 0.f, d1 = 0.f;
#pragma unroll
  for (int j = 0; j < MDIM; ++j) {
    d0 += __shfl(u, j, 16) * c2row[j];
    d1 += __shfl(t0, j, 16) * c2row[j];
  }
  const float tens0 = c1_0 + c2c - 2.f * d0;
  const float tens1 = c1_r + c2c - 2.f * d1;

  float acc = 0.f;
#pragma unroll
  for (int k = 0; k < KDIM; ++k) {
    float tv = (k == 0) ? tens0 : tens1;
    acc += Tc[k] * (w0 * Mc[k] + a * tv);
  }
  if (!act) acc = 0.f;
  acc = sum16(acc);
  if (lane == 0) out[n * TDIM + t] = acc;
}

extern "C" void kernel_launch(void* const* d_in, const int* in_sizes, int n_in,
                              void* d_out, int out_size, void* d_ws, size_t ws_size,
                              hipStream_t stream) {
  const float* x         = (const float*)d_in[0];
  // d_in[1] = edge_index (unused; `neighbors` is its padded form)
  const int*   neighbors = (const int*)d_in[2];
  const float* templates = (const float*)d_in[3];
  const float* tfeat     = (const float*)d_in[4];
  const float* alpha     = (const float*)d_in[5];
  float* out = (float*)d_out;

  const int n_nodes = in_sizes[0] / FDIM;  // 15000
  fgw_kernel<<<n_nodes, 256, 0, stream>>>(x, neighbors, templates, tfeat,
                                          alpha, out);
}

// Round 2
// 2147.678 us; speedup vs baseline: 3.1346x; 3.1346x over previous
//
#include <hip/hip_runtime.h>

#define FDIM 16
#define TDIM 16
#define MDIM 10
#define KDIM 17
#define NCG 5
#define NSINK 25

// DPP move within a 16-lane row (VALU, avoids the shared LDS unit).
template <int CTRL>
__device__ __forceinline__ float dppf(float x) {
  return __int_as_float(__builtin_amdgcn_update_dpp(
      0, __float_as_int(x), CTRL, 0xF, 0xF, true));
}
// All-reduce over the 16-lane row via row_ror:1,2,4,8.
__device__ __forceinline__ float sum16(float v) {
  v += dppf<0x121>(v);
  v += dppf<0x122>(v);
  v += dppf<0x124>(v);
  v += dppf<0x128>(v);
  return v;
}
__device__ __forceinline__ float max16(float v) {
  v = fmaxf(v, dppf<0x121>(v));
  v = fmaxf(v, dppf<0x122>(v));
  v = fmaxf(v, dppf<0x124>(v));
  v = fmaxf(v, dppf<0x128>(v));
  return v;
}

__global__ __launch_bounds__(256) void fgw_kernel(
    const float* __restrict__ x,        // [N,F]
    const int* __restrict__ nbrs,       // [N,K]
    const float* __restrict__ tmpl,     // [T,M,M]
    const float* __restrict__ tfeat,    // [T,M,F]
    const float* __restrict__ alpha,    // [1]
    float* __restrict__ out)            // [N,T]
{
  const int n = blockIdx.x;
  const int tid = threadIdx.x;
  const int t = tid >> 4;          // template id: 16 groups per block
  const int lane = tid & 15;       // column m within group
  const bool act = lane < MDIM;
  const int m = act ? lane : 0;

  __shared__ int sIdx[KDIM];
  __shared__ float sF1[KDIM][FDIM];

  if (tid < KDIM) sIdx[tid] = nbrs[n * KDIM + tid];
  __syncthreads();
  for (int i = tid; i < KDIM * FDIM; i += 256)
    sF1[i >> 4][i & 15] = x[sIdx[i >> 4] * FDIM + (i & 15)];
  __syncthreads();

  const float a  = alpha[0];
  const float w0 = 1.f - a;       // weight on Mcost in G
  const float w2 = 2.f * a;       // weight on tens in G

  // per-lane template data (column m of template t)
  float c2row[MDIM], f2[FDIM];
#pragma unroll
  for (int j = 0; j < MDIM; ++j)
    c2row[j] = act ? tmpl[(t * MDIM + m) * MDIM + j] : 0.f;
#pragma unroll
  for (int f = 0; f < FDIM; ++f)
    f2[f] = act ? tfeat[(t * MDIM + m) * FDIM + f] : 0.f;

  float n2 = 0.f, c2c = 0.f;
#pragma unroll
  for (int f = 0; f < FDIM; ++f) n2 += f2[f] * f2[f];
#pragma unroll
  for (int j = 0; j < MDIM; ++j) c2c += c2row[j] * c2row[j];
  c2c *= 0.1f;  // (C2*C2) @ h2, h2 = 1/10

  // M0 = (1-a) * Mcost column m
  float M0[KDIM];
#pragma unroll
  for (int k = 0; k < KDIM; ++k) {
    float dot = 0.f, n1 = 0.f;
#pragma unroll
    for (int f = 0; f < FDIM; ++f) {
      float v = sF1[k][f];
      dot += v * f2[f];
      n1 += v * v;
    }
    M0[k] = w0 * (n1 + n2 - 2.f * dot);
  }
  // extremes over k>=1 for the exact max|G| shortcut (G affine in M0)
  float M0max = M0[1], M0min = M0[1];
#pragma unroll
  for (int k = 2; k < KDIM; ++k) {
    M0max = fmaxf(M0max, M0[k]);
    M0min = fminf(M0min, M0[k]);
  }

  const float c1_0 = 16.f / 17.f;   // (C1 @ h1)[0]
  const float c1_r = 1.f / 17.f;    // (C1 @ h1)[k>=1]
  const float CN  = -28.8539008178f; // -log2(e)/eps, eps = 0.05
  const float L17 = 4.0874628413f;   // log2(17): folds h1 into K (K'' = 17 K)

  float Tc[KDIM];
#pragma unroll
  for (int k = 0; k < KDIM; ++k) Tc[k] = act ? (1.f / 170.f) : 0.f;

  float Kx[KDIM], uu[KDIM];

#pragma unroll 1
  for (int it = 0; it < NCG; ++it) {
    // ---- tens(Tc): star C1 collapses C1*Tc*C2^T to two scalars per column
    float cs = 0.f;
#pragma unroll
    for (int k = 1; k < KDIM; ++k) cs += Tc[k];
    float t0 = Tc[0];
    float d0 = 0.f, d1 = 0.f;
#pragma unroll
    for (int j = 0; j < MDIM; ++j) {
      d0 += __shfl(cs, j, 16) * c2row[j];
      d1 += __shfl(t0, j, 16) * c2row[j];
    }
    const float tens0 = c1_0 + c2c - 2.f * d0;  // row k = 0
    const float tens1 = c1_r + c2c - 2.f * d1;  // rows k >= 1

    // ---- scale = max|G| (exact via affinity in M0), K'' = 17*exp(-G/(sc*eps))
    float g0 = fmaf(w2, tens0, M0[0]);
    float ga = fmaf(w2, tens1, M0max);
    float gb = fmaf(w2, tens1, M0min);
    float mabs = fmaxf(fabsf(g0), fmaxf(fabsf(ga), fabsf(gb)));
    if (!act) mabs = 0.f;
    mabs = max16(mabs);
    const float nsc = CN / (mabs + 1e-12f);
#pragma unroll
    for (int k = 0; k < KDIM; ++k) {
      float g = fmaf(w2, (k == 0 ? tens0 : tens1), M0[k]);
      float arg = fmaf(nsc, g, L17);
      Kx[k] = act ? __builtin_amdgcn_exp2f(arg) : 0.f;  // in [3.5e-8, 8.7e9]
    }

    // ---- multiplicative Sinkhorn: u = 1/(K''v) (h1-exact), v = 1.7/(K''^T u)
    float v = act ? 1.f : 0.f;
#pragma unroll 1
    for (int s = 0; s < NSINK; ++s) {
      if (s) {  // gauge renorm (exact: cancels by homogeneity), keeps fp32 range
        float vm = max16(v);
        v *= __builtin_amdgcn_rcpf(vm);
      }
#pragma unroll
      for (int k = 0; k < KDIM; ++k)
        uu[k] = __builtin_amdgcn_rcpf(sum16(Kx[k] * v));
      float z0 = 0.f, z1 = 0.f;
#pragma unroll
      for (int k = 0; k < KDIM; k += 2) z0 = fmaf(Kx[k], uu[k], z0);
#pragma unroll
      for (int k = 1; k < KDIM; k += 2) z1 = fmaf(Kx[k], uu[k], z1);
      float z = z0 + z1;
      v = act ? 1.7f * __builtin_amdgcn_rcpf(z) : 0.f;  // 17*h2 = 1.7 (exact)
    }

    // ---- CG step: Tc = (1-g)Tc + g*S, S = u K v = u K'' v / 17
    const float gamma = 2.f / (float)(it + 2);
    const float om = 1.f - gamma;
    const float gv = gamma * (1.f / 17.f) * v;  // per-lane
#pragma unroll
    for (int k = 0; k < KDIM; ++k)
      Tc[k] = fmaf(gv * uu[k], Kx[k], om * Tc[k]);
  }

  // ---- final tens with converged Tc, then fgw = sum Tc*( M0 + a*tens )
  float cs = 0.f;
#pragma unroll
  for (int k = 1; k < KDIM; ++k) cs += Tc[k];
  float t0 = Tc[0];
  float d0 = 0.f, d1 = 0.f;
#pragma unroll
  for (int j = 0; j < MDIM; ++j) {
    d0 += __shfl(cs, j, 16) * c2row[j];
    d1 += __shfl(t0, j, 16) * c2row[j];
  }
  const float tens0 = c1_0 + c2c - 2.f * d0;
  const float tens1 = c1_r + c2c - 2.f * d1;

  float acc = 0.f;
#pragma unroll
  for (int k = 0; k < KDIM; ++k) {
    float tv = (k == 0) ? tens0 : tens1;
    acc += Tc[k] * fmaf(a, tv, M0[k]);
  }
  if (!act) acc = 0.f;
  acc = sum16(acc);
  if (lane == 0) out[n * TDIM + t] = acc;
}

extern "C" void kernel_launch(void* const* d_in, const int* in_sizes, int n_in,
                              void* d_out, int out_size, void* d_ws, size_t ws_size,
                              hipStream_t stream) {
  const float* x         = (const float*)d_in[0];
  // d_in[1] = edge_index (unused; `neighbors` is its padded form)
  const int*   neighbors = (const int*)d_in[2];
  const float* templates = (const float*)d_in[3];
  const float* tfeat     = (const float*)d_in[4];
  const float* alpha     = (const float*)d_in[5];
  float* out = (float*)d_out;

  const int n_nodes = in_sizes[0] / FDIM;  // 15000
  fgw_kernel<<<n_nodes, 256, 0, stream>>>(x, neighbors, templates, tfeat,
                                          alpha, out);
}

// Round 3
// 1137.257 us; speedup vs baseline: 5.9195x; 1.8885x over previous
//
#include <hip/hip_runtime.h>

#define FDIM 16
#define TDIM 16
#define MDIM 10
#define KDIM 17
#define NCG 5
#define NSINK 25

// DPP move (VALU). quad_perm controls: xor1 = [1,0,3,2] = 0xB1, xor2 = [2,3,0,1] = 0x4E.
template <int CTRL>
__device__ __forceinline__ float dppf(float x) {
  return __int_as_float(__builtin_amdgcn_update_dpp(
      0, __float_as_int(x), CTRL, 0xF, 0xF, true));
}
// lane ^= 4 via ds_swizzle (LDS pipe — idle in this kernel). offset 0x101F = xor 4, and 0x1F.
__device__ __forceinline__ float swz_xor4(float x) {
  return __int_as_float(__builtin_amdgcn_ds_swizzle(__float_as_int(x), 0x101F));
}
// all-reduce over the 8-lane group: 2 DPP stages + 1 swizzle stage
__device__ __forceinline__ float sum8(float v) {
  v += dppf<0xB1>(v);
  v += dppf<0x4E>(v);
  v += swz_xor4(v);
  return v;
}
__device__ __forceinline__ float max8(float v) {
  v = fmaxf(v, dppf<0xB1>(v));
  v = fmaxf(v, dppf<0x4E>(v));
  v = fmaxf(v, swz_xor4(v));
  return v;
}
__device__ __forceinline__ float bperm(int byte_addr, float x) {
  return __int_as_float(__builtin_amdgcn_ds_bpermute(byte_addr, __float_as_int(x)));
}

__global__ __launch_bounds__(256) void fgw_kernel(
    const float* __restrict__ x,        // [N,F]
    const int* __restrict__ nbrs,       // [N,K]
    const float* __restrict__ tmpl,     // [T,M,M]
    const float* __restrict__ tfeat,    // [T,M,F]
    const float* __restrict__ alpha,    // [1]
    float* __restrict__ out)            // [N,T]
{
  const int tid  = threadIdx.x;
  const int nl   = tid >> 7;          // node-local 0/1 (2 nodes per block)
  const int t    = (tid >> 3) & 15;   // template
  const int lane = tid & 7;           // column m (main cols 0-7)
  const bool act2 = lane < 2;         // lanes carrying extra cols 8,9
  const int node = blockIdx.x * 2 + nl;

  __shared__ int   sIdx[2 * KDIM];
  __shared__ float sF1[2][KDIM][FDIM];
  __shared__ float sM0[2 * 16 * KDIM * MDIM];   // [nl][t][k][m], private per thread-group

  if (tid < 2 * KDIM)
    sIdx[tid] = nbrs[(blockIdx.x * 2 + tid / KDIM) * KDIM + tid % KDIM];
  __syncthreads();
  for (int i = tid; i < 2 * KDIM * FDIM; i += 256) {
    int nn = (i >= KDIM * FDIM);
    int r = i - nn * KDIM * FDIM;
    sF1[nn][r >> 4][r & 15] = x[sIdx[nn * KDIM + (r >> 4)] * FDIM + (r & 15)];
  }
  __syncthreads();

  const float a  = alpha[0];
  const float w0 = 1.f - a;
  const float w2 = 2.f * a;

  // per-lane template data: main col m=lane, extra col 8+lane (lanes 0,1)
  float c2row[MDIM], c2rowe[MDIM], f2[FDIM], f2e[FDIM];
#pragma unroll
  for (int j = 0; j < MDIM; ++j) {
    c2row[j]  = tmpl[(t * MDIM + lane) * MDIM + j];
    c2rowe[j] = act2 ? tmpl[(t * MDIM + 8 + lane) * MDIM + j] : 0.f;
  }
#pragma unroll
  for (int f = 0; f < FDIM; ++f) {
    f2[f]  = tfeat[(t * MDIM + lane) * FDIM + f];
    f2e[f] = act2 ? tfeat[(t * MDIM + 8 + lane) * FDIM + f] : 0.f;
  }
  float n2 = 0.f, n2e = 0.f, c2c = 0.f, c2ce = 0.f;
#pragma unroll
  for (int f = 0; f < FDIM; ++f) { n2 += f2[f] * f2[f]; n2e += f2e[f] * f2e[f]; }
#pragma unroll
  for (int j = 0; j < MDIM; ++j) { c2c += c2row[j] * c2row[j]; c2ce += c2rowe[j] * c2rowe[j]; }
  c2c *= 0.1f; c2ce *= 0.1f;

  // M0 = (1-a)*Mcost -> LDS; track per-column k=0 value, max/min over k>=1, column sum
  const int gb = (nl * 16 + t) * (KDIM * MDIM);
  float* m0p = &sM0[gb];
  const int eoff = act2 ? (8 + lane) : 9;   // clamped extra read offset (masked later)

  float M00 = 0.f, M00e = 0.f, M0mx = -1e30f, M0mn = 1e30f, M0mxe = -1e30f, M0mne = 1e30f;
  float ipm0 = 0.f, ipm0e = 0.f;
#pragma unroll
  for (int k = 0; k < KDIM; ++k) {
    float dot = 0.f, dote = 0.f, n1 = 0.f;
#pragma unroll
    for (int f = 0; f < FDIM; ++f) {
      float vv = sF1[nl][k][f];
      n1 = fmaf(vv, vv, n1);
      dot = fmaf(vv, f2[f], dot);
      dote = fmaf(vv, f2e[f], dote);
    }
    float M0k  = w0 * (n1 + n2  - 2.f * dot);
    float M0ke = w0 * (n1 + n2e - 2.f * dote);
    m0p[k * MDIM + lane] = M0k;
    if (act2) m0p[k * MDIM + 8 + lane] = M0ke;
    ipm0 += M0k; ipm0e += M0ke;
    if (k == 0) { M00 = M0k; M00e = M0ke; }
    else {
      M0mx = fmaxf(M0mx, M0k);  M0mn = fminf(M0mn, M0k);
      M0mxe = fmaxf(M0mxe, M0ke); M0mne = fminf(M0mne, M0ke);
    }
  }
  if (!act2) { M00e = 0.f; M0mxe = 0.f; M0mne = 0.f; ipm0e = 0.f; }

  const float c1_0 = 16.f / 17.f;
  const float c1_r = 1.f / 17.f;
  const float CN  = -28.8539008178f;  // -log2(e)/eps
  const float L17 = 4.0874628413f;    // log2(17): folds h1 into K

  // tracked functionals of Tc: t0 = Tc[0][m], cs = sum_{k>=1} Tc[k][m], ipm = <Tc,M0> column part
  float t0 = 1.f / 170.f, cs = 16.f / 170.f, ipm = ipm0 * (1.f / 170.f);
  float t0e = act2 ? 1.f / 170.f : 0.f, cse = act2 ? 16.f / 170.f : 0.f, ipme = ipm0e * (1.f / 170.f);

  int laneid = __builtin_amdgcn_mbcnt_hi(~0u, __builtin_amdgcn_mbcnt_lo(~0u, 0u));
  const int lbase = (laneid & 56) << 2;   // byte base of this 8-lane group for bpermute

  float Kx[KDIM], Ke[KDIM], uu[KDIM];
  float d0, d1, d0e, d1e;

  auto calc_d = [&]() {
    d0 = d1 = d0e = d1e = 0.f;
#pragma unroll
    for (int j = 0; j < 8; ++j) {
      int ad = lbase | (j << 2);
      float cb = bperm(ad, cs), tb = bperm(ad, t0);
      d0  = fmaf(cb, c2row[j], d0);   d1  = fmaf(tb, c2row[j], d1);
      d0e = fmaf(cb, c2rowe[j], d0e); d1e = fmaf(tb, c2rowe[j], d1e);
    }
#pragma unroll
    for (int j = 0; j < 2; ++j) {
      int ad = lbase | (j << 2);
      float cb = bperm(ad, cse), tb = bperm(ad, t0e);
      d0  = fmaf(cb, c2row[8 + j], d0);   d1  = fmaf(tb, c2row[8 + j], d1);
      d0e = fmaf(cb, c2rowe[8 + j], d0e); d1e = fmaf(tb, c2rowe[8 + j], d1e);
    }
  };

#pragma unroll 1
  for (int it = 0; it < NCG; ++it) {
    calc_d();
    float tens0  = c1_0 + c2c  - 2.f * d0;
    float tens1  = c1_r + c2c  - 2.f * d1;
    float tens0e = c1_0 + c2ce - 2.f * d0e;
    float tens1e = c1_r + c2ce - 2.f * d1e;

    // scale = max|G| (exact: G affine in M0 per row-class)
    float g0 = fmaf(w2, tens0, M00);
    float ga = fmaf(w2, tens1, M0mx);
    float gbv = fmaf(w2, tens1, M0mn);
    float mabs = fmaxf(fabsf(g0), fmaxf(fabsf(ga), fabsf(gbv)));
    float g0e = fmaf(w2, tens0e, M00e);
    float gae = fmaf(w2, tens1e, M0mxe);
    float gbe = fmaf(w2, tens1e, M0mne);
    float mabse = fmaxf(fabsf(g0e), fmaxf(fabsf(gae), fabsf(gbe)));
    mabs = fmaxf(mabs, act2 ? mabse : 0.f);
    mabs = max8(mabs);
    const float nsc = CN / (mabs + 1e-12f);

    const float nw2 = nsc * w2;
    const float A0 = fmaf(nw2, tens0, L17),  A1 = fmaf(nw2, tens1, L17);
    const float A0e = fmaf(nw2, tens0e, L17), A1e = fmaf(nw2, tens1e, L17);
#pragma unroll
    for (int k = 0; k < KDIM; ++k) {
      float m0k = m0p[k * MDIM + lane];
      Kx[k] = __builtin_amdgcn_exp2f(fmaf(nsc, m0k, k ? A1 : A0));
      float m0ke = m0p[k * MDIM + eoff];
      float ev = __builtin_amdgcn_exp2f(fmaf(nsc, m0ke, k ? A1e : A0e));
      Ke[k] = act2 ? ev : 0.f;
    }

    // multiplicative Sinkhorn (gauge-renormalized), 8-lane groups + extra-col regs
    float v = 1.f, ve = act2 ? 1.f : 0.f;
    float z = 0.f, ze = 0.f;
#pragma unroll 1
    for (int s = 0; s < NSINK; ++s) {
      if (s) {  // gauge renorm: exact cancellation by homogeneity
        float vm = max8(fmaxf(v, ve));
        float r = __builtin_amdgcn_rcpf(vm);
        v *= r; ve *= r;
      }
#pragma unroll
      for (int k = 0; k < KDIM; ++k) {
        float P = fmaf(Ke[k], ve, Kx[k] * v);
        P += dppf<0xB1>(P);
        P += dppf<0x4E>(P);
        P += swz_xor4(P);
        uu[k] = __builtin_amdgcn_rcpf(P);   // h1-exact: 17 folded via L17
      }
      z = 0.f; ze = 0.f;
#pragma unroll
      for (int k = 0; k < KDIM; ++k) {
        z  = fmaf(Kx[k], uu[k], z);
        ze = fmaf(Ke[k], uu[k], ze);
      }
      v = 1.7f * __builtin_amdgcn_rcpf(z);                      // 17*h2
      ve = act2 ? 1.7f * __builtin_amdgcn_rcpf(ze) : 0.f;
    }

    // CG update of (t0, cs, ipm) from S = uu*K''*v/17  (z, ze are from final uu)
    float ips = 0.f, ipse = 0.f;
#pragma unroll
    for (int k = 0; k < KDIM; ++k) {
      ips  = fmaf(uu[k] * Kx[k], m0p[k * MDIM + lane], ips);
      ipse = fmaf(uu[k] * Ke[k], m0p[k * MDIM + eoff], ipse);
    }
    const float s17 = 1.f / 17.f;
    float colS  = v * z * s17;
    float t0S   = uu[0] * Kx[0] * v * s17;
    float csS   = colS - t0S;
    float ipS   = ips * v * s17;
    float colSe = ve * ze * s17;
    float t0Se  = uu[0] * Ke[0] * ve * s17;
    float csSe  = colSe - t0Se;
    float ipSe  = ipse * ve * s17;

    const float gamma = 2.f / (float)(it + 2);
    const float om = 1.f - gamma;
    t0  = om * t0  + gamma * t0S;   cs  = om * cs  + gamma * csS;   ipm  = om * ipm  + gamma * ipS;
    t0e = om * t0e + gamma * t0Se;  cse = om * cse + gamma * csSe;  ipme = om * ipme + gamma * ipSe;
  }

  // final: fgw = <T,M0> + a*<tens(T),T>, tens contraction via (t0, cs) only
  calc_d();
  float tens0  = c1_0 + c2c  - 2.f * d0;
  float tens1  = c1_r + c2c  - 2.f * d1;
  float tens0e = c1_0 + c2ce - 2.f * d0e;
  float tens1e = c1_r + c2ce - 2.f * d1e;

  float acc = ipm + a * (tens0 * t0 + tens1 * cs)
            + ipme + a * (tens0e * t0e + tens1e * cse);
  acc = sum8(acc);
  if (lane == 0) out[node * TDIM + t] = acc;
}

extern "C" void kernel_launch(void* const* d_in, const int* in_sizes, int n_in,
                              void* d_out, int out_size, void* d_ws, size_t ws_size,
                              hipStream_t stream) {
  const float* x         = (const float*)d_in[0];
  // d_in[1] = edge_index (unused; `neighbors` is its padded form)
  const int*   neighbors = (const int*)d_in[2];
  const float* templates = (const float*)d_in[3];
  const float* tfeat     = (const float*)d_in[4];
  const float* alpha     = (const float*)d_in[5];
  float* out = (float*)d_out;

  const int n_nodes = in_sizes[0] / FDIM;  // 15000
  fgw_kernel<<<n_nodes / 2, 256, 0, stream>>>(x, neighbors, templates, tfeat,
                                              alpha, out);
}

// Round 4
// 980.255 us; speedup vs baseline: 6.8676x; 1.1602x over previous
//
#include <hip/hip_runtime.h>

#define FDIM 16
#define TDIM 16
#define MDIM 10
#define KDIM 17
#define NCG 5

typedef float v2f __attribute__((ext_vector_type(2)));

// DPP move (VALU). quad_perm xor1 = 0xB1, xor2 = 0x4E, row_half_mirror = 0x141.
template <int CTRL>
__device__ __forceinline__ float dppf(float x) {
  return __int_as_float(__builtin_amdgcn_update_dpp(
      0, __float_as_int(x), CTRL, 0xF, 0xF, true));
}
// 8-lane all-reduce entirely on VALU: xor1, xor2, then half-mirror (l <-> 7-l).
__device__ __forceinline__ float rsum8(float v) {
  v += dppf<0xB1>(v);
  v += dppf<0x4E>(v);
  v += dppf<0x141>(v);
  return v;
}
__device__ __forceinline__ float rmax8(float v) {
  v = fmaxf(v, dppf<0xB1>(v));
  v = fmaxf(v, dppf<0x4E>(v));
  v = fmaxf(v, dppf<0x141>(v));
  return v;
}
__device__ __forceinline__ float bperm(int byte_addr, float x) {
  return __int_as_float(__builtin_amdgcn_ds_bpermute(byte_addr, __float_as_int(x)));
}

__global__ __launch_bounds__(256) void fgw_kernel(
    const float* __restrict__ x,        // [N,F]
    const int* __restrict__ nbrs,       // [N,K]
    const float* __restrict__ tmpl,     // [T,M,M]
    const float* __restrict__ tfeat,    // [T,M,F]
    const float* __restrict__ alpha,    // [1]
    float* __restrict__ out)            // [N,T]
{
  const int tid  = threadIdx.x;
  const int nl   = tid >> 7;          // node-local 0/1
  const int t    = (tid >> 3) & 15;   // template
  const int lane = tid & 7;           // main column m = lane
  const bool act2 = lane < 2;         // lanes carrying extra cols 8,9

  __shared__ int   sIdx[2 * KDIM];
  __shared__ v2f   sF1p[2][KDIM][FDIM];          // duplicated {v,v} for pk broadcast
  __shared__ float sN1[2 * KDIM];
  __shared__ float sM0w[2 * 16 * MDIM * 18];     // [nl][t][m][k], k-stride 18

  if (tid < 2 * KDIM)
    sIdx[tid] = nbrs[(blockIdx.x * 2 + tid / KDIM) * KDIM + tid % KDIM];
  __syncthreads();
  for (int i = tid; i < 2 * KDIM * FDIM; i += 256) {
    int nn = (i >= KDIM * FDIM);
    int r = i - nn * KDIM * FDIM;
    float val = x[sIdx[nn * KDIM + (r >> 4)] * FDIM + (r & 15)];
    v2f dup = {val, val};
    sF1p[nn][r >> 4][r & 15] = dup;
  }
  __syncthreads();
  if (tid < 2 * KDIM) {
    int nn = tid / KDIM, k = tid % KDIM;
    float s = 0.f;
#pragma unroll
    for (int f = 0; f < FDIM; ++f) {
      float vv = sF1p[nn][k][f].x;
      s = fmaf(vv, vv, s);
    }
    sN1[tid] = s;
  }
  __syncthreads();

  const float a  = alpha[0];
  const float w0 = 1.f - a;
  const float w2 = 2.f * a;

  // template data: main col m=lane, extra col 8+lane (lanes 0,1) packed as .y
  float c2row[MDIM], c2rowe[MDIM];
  v2f f2p[FDIM];
#pragma unroll
  for (int j = 0; j < MDIM; ++j) {
    c2row[j]  = tmpl[(t * MDIM + lane) * MDIM + j];
    c2rowe[j] = act2 ? tmpl[(t * MDIM + 8 + lane) * MDIM + j] : 0.f;
  }
#pragma unroll
  for (int f = 0; f < FDIM; ++f) {
    v2f tmp = {tfeat[(t * MDIM + lane) * FDIM + f],
               act2 ? tfeat[(t * MDIM + 8 + lane) * FDIM + f] : 0.f};
    f2p[f] = tmp;
  }
  v2f n2p = {0.f, 0.f};
#pragma unroll
  for (int f = 0; f < FDIM; ++f) n2p = f2p[f] * f2p[f] + n2p;
  float c2c = 0.f, c2ce = 0.f;
#pragma unroll
  for (int j = 0; j < MDIM; ++j) {
    c2c  = fmaf(c2row[j], c2row[j], c2c);
    c2ce = fmaf(c2rowe[j], c2rowe[j], c2ce);
  }
  c2c *= 0.1f; c2ce *= 0.1f;

  // M0 = (1-a)*Mcost -> LDS [m][k] (k-stride 18); per-column stats in regs
  const int base = (nl * 16 + t) * MDIM;        // column index base
  const int cw  = (base + lane) * 18;           // main column word offset
  const int eoff = act2 ? (8 + lane) : 9;
  const int ce  = (base + eoff) * 18;           // extra column (clamped read)
  const int cwe = (base + 8 + lane) * 18;       // extra column (store, lanes 0,1)

  float M00 = 0.f, M00e = 0.f, M0mx = -1e30f, M0mn = 1e30f, M0mxe = -1e30f, M0mne = 1e30f;
  float ipm0 = 0.f, ipm0e = 0.f;
#pragma unroll
  for (int k = 0; k < KDIM; ++k) {
    v2f dotp = {0.f, 0.f};
#pragma unroll
    for (int f = 0; f < FDIM; ++f) dotp = sF1p[nl][k][f] * f2p[f] + dotp;
    float n1 = sN1[nl * KDIM + k];
    float M0k  = w0 * (n1 + n2p.x - 2.f * dotp.x);
    float M0ke = w0 * (n1 + n2p.y - 2.f * dotp.y);
    sM0w[cw + k] = M0k;
    if (act2) sM0w[cwe + k] = M0ke;
    ipm0 += M0k; ipm0e += M0ke;
    if (k == 0) { M00 = M0k; M00e = M0ke; }
    else {
      M0mx = fmaxf(M0mx, M0k);  M0mn = fminf(M0mn, M0k);
      M0mxe = fmaxf(M0mxe, M0ke); M0mne = fminf(M0mne, M0ke);
    }
  }
  if (!act2) { M00e = 0.f; M0mxe = 0.f; M0mne = 0.f; ipm0e = 0.f; }

  const float c1_0 = 16.f / 17.f;
  const float c1_r = 1.f / 17.f;
  const float CN  = -28.8539008178f;  // -log2(e)/eps
  const float L17 = 4.0874628413f;    // log2(17): folds h1 into K

  float t0 = 1.f / 170.f, cs = 16.f / 170.f, ipm = ipm0 * (1.f / 170.f);
  float t0e = act2 ? 1.f / 170.f : 0.f, cse = act2 ? 16.f / 170.f : 0.f;
  float ipme = ipm0e * (1.f / 170.f);

  int laneid = __builtin_amdgcn_mbcnt_hi(~0u, __builtin_amdgcn_mbcnt_lo(~0u, 0u));
  const int lbase = (laneid & 56) << 2;   // byte base of this 8-lane group

  v2f KxP[8], KeP[8], u2[8];
  float Kx16, Ke16, u16, zs, zEs, v, ve;
  float d0, d1, d0e, d1e;

  auto calc_d = [&]() {
    d0 = d1 = d0e = d1e = 0.f;
#pragma unroll
    for (int j = 0; j < 8; ++j) {
      int ad = lbase | (j << 2);
      float cb = bperm(ad, cs), tb = bperm(ad, t0);
      d0  = fmaf(cb, c2row[j], d0);   d1  = fmaf(tb, c2row[j], d1);
      d0e = fmaf(cb, c2rowe[j], d0e); d1e = fmaf(tb, c2rowe[j], d1e);
    }
#pragma unroll
    for (int j = 0; j < 2; ++j) {
      int ad = lbase | (j << 2);
      float cb = bperm(ad, cse), tb = bperm(ad, t0e);
      d0  = fmaf(cb, c2row[8 + j], d0);   d1  = fmaf(tb, c2row[8 + j], d1);
      d0e = fmaf(cb, c2rowe[8 + j], d0e); d1e = fmaf(tb, c2rowe[8 + j], d1e);
    }
  };

  auto ITER = [&](bool dorenorm) {
    if (dorenorm) {  // gauge renorm: exact cancellation by homogeneity
      float vm = rmax8(fmaxf(v, ve));
      float r = __builtin_amdgcn_rcpf(vm);
      v *= r; ve *= r;
    }
    v2f vv2 = {v, v}, vve2 = {ve, ve};
    // u-phase: u_k = 1/(K''v) (h1-exact via L17 fold)
#pragma unroll
    for (int j = 0; j < 8; ++j) {
      v2f q = KxP[j] * vv2 + KeP[j] * vve2;
      u2[j].x = __builtin_amdgcn_rcpf(rsum8(q.x));
      u2[j].y = __builtin_amdgcn_rcpf(rsum8(q.y));
    }
    {
      float q16 = fmaf(Ke16, ve, Kx16 * v);
      u16 = __builtin_amdgcn_rcpf(rsum8(q16));
    }
    // z-phase: z_m = sum_k K''[k][m] u_k (lane-local)
    v2f z2 = {0.f, 0.f}, zE2 = {0.f, 0.f};
#pragma unroll
    for (int j = 0; j < 8; ++j) {
      z2  = KxP[j] * u2[j] + z2;
      zE2 = KeP[j] * u2[j] + zE2;
    }
    zs  = fmaf(Kx16, u16, z2.x + z2.y);
    zEs = fmaf(Ke16, u16, zE2.x + zE2.y);
    v  = 1.7f * __builtin_amdgcn_rcpf(zs);                      // 17*h2
    ve = act2 ? 1.7f * __builtin_amdgcn_rcpf(zEs) : 0.f;        // kill dead lanes
  };

#pragma unroll 1
  for (int it = 0; it < NCG; ++it) {
    calc_d();
    float tens0  = c1_0 + c2c  - 2.f * d0;
    float tens1  = c1_r + c2c  - 2.f * d1;
    float tens0e = c1_0 + c2ce - 2.f * d0e;
    float tens1e = c1_r + c2ce - 2.f * d1e;

    // scale = max|G| (exact: G affine in M0 per row-class)
    float g0 = fmaf(w2, tens0, M00);
    float ga = fmaf(w2, tens1, M0mx);
    float gb = fmaf(w2, tens1, M0mn);
    float mabs = fmaxf(fabsf(g0), fmaxf(fabsf(ga), fabsf(gb)));
    float g0e = fmaf(w2, tens0e, M00e);
    float gae = fmaf(w2, tens1e, M0mxe);
    float gbe = fmaf(w2, tens1e, M0mne);
    float mabse = fmaxf(fabsf(g0e), fmaxf(fabsf(gae), fabsf(gbe)));
    mabs = rmax8(fmaxf(mabs, act2 ? mabse : 0.f));
    const float nsc = CN / (mabs + 1e-12f);

    // K'' build, packed over k-pairs; Ke left unmasked (ve=0 guards dead lanes)
    const float nw2 = nsc * w2;
    float A0  = fmaf(nw2, tens0, L17),  A1  = fmaf(nw2, tens1, L17);
    float A0e = fmaf(nw2, tens0e, L17), A1e = fmaf(nw2, tens1e, L17);
    v2f nscv = {nsc, nsc};
    v2f A2  = {A0, A1};
    v2f A2e = {A0e, A1e};
#pragma unroll
    for (int j = 0; j < 8; ++j) {
      v2f m2 = *(const v2f*)&sM0w[cw + 2 * j];
      v2f arg = nscv * m2 + A2;
      KxP[j].x = __builtin_amdgcn_exp2f(arg.x);
      KxP[j].y = __builtin_amdgcn_exp2f(arg.y);
      v2f me = *(const v2f*)&sM0w[ce + 2 * j];
      v2f arge = nscv * me + A2e;
      KeP[j].x = __builtin_amdgcn_exp2f(arge.x);
      KeP[j].y = __builtin_amdgcn_exp2f(arge.y);
      if (j == 0) { A2.x = A1; A2e.x = A1e; }
    }
    Kx16 = __builtin_amdgcn_exp2f(fmaf(nsc, sM0w[cw + 16], A1));
    Ke16 = __builtin_amdgcn_exp2f(fmaf(nsc, sM0w[ce + 16], A1e));

    // 25 multiplicative Sinkhorn iterations; renorm every 2nd (range-safe)
    v = 1.f; ve = act2 ? 1.f : 0.f;
    ITER(false); ITER(false);
#pragma unroll 1
    for (int sp = 0; sp < 11; ++sp) { ITER(true); ITER(false); }
    ITER(true);

    // CG update of (t0, cs, ipm) from S = u K'' v / 17
    v2f ipsP = {0.f, 0.f}, ipsPe = {0.f, 0.f};
#pragma unroll
    for (int j = 0; j < 8; ++j) {
      v2f m2 = *(const v2f*)&sM0w[cw + 2 * j];
      v2f me = *(const v2f*)&sM0w[ce + 2 * j];
      v2f tK = KxP[j] * u2[j];
      v2f tE = KeP[j] * u2[j];
      ipsP  = tK * m2 + ipsP;
      ipsPe = tE * me + ipsPe;
    }
    float ips  = fmaf(Kx16 * u16, sM0w[cw + 16], ipsP.x + ipsP.y);
    float ipse = fmaf(Ke16 * u16, sM0w[ce + 16], ipsPe.x + ipsPe.y);

    const float s17 = 1.f / 17.f;
    float colS  = v * zs * s17;
    float t0S   = u2[0].x * KxP[0].x * v * s17;
    float csS   = colS - t0S;
    float ipS   = ips * v * s17;
    float colSe = ve * zEs * s17;           // ve = 0 on dead lanes -> all-e terms 0
    float t0Se  = u2[0].x * KeP[0].x * ve * s17;
    float csSe  = colSe - t0Se;
    float ipSe  = ipse * ve * s17;

    const float gamma = 2.f / (float)(it + 2);
    const float om = 1.f - gamma;
    t0  = om * t0  + gamma * t0S;   cs  = om * cs  + gamma * csS;   ipm  = om * ipm  + gamma * ipS;
    t0e = om * t0e + gamma * t0Se;  cse = om * cse + gamma * csSe;  ipme = om * ipme + gamma * ipSe;
  }

  // final: fgw = <T,M0> + a*<tens(T),T> via (t0, cs) functionals
  calc_d();
  float tens0  = c1_0 + c2c  - 2.f * d0;
  float tens1  = c1_r + c2c  - 2.f * d1;
  float tens0e = c1_0 + c2ce - 2.f * d0e;
  float tens1e = c1_r + c2ce - 2.f * d1e;

  float acc = ipm + a * (tens0 * t0 + tens1 * cs)
            + ipme + a * (tens0e * t0e + tens1e * cse);
  acc = rsum8(acc);
  if (lane == 0) out[(blockIdx.x * 2 + nl) * TDIM + t] = acc;
}

extern "C" void kernel_launch(void* const* d_in, const int* in_sizes, int n_in,
                              void* d_out, int out_size, void* d_ws, size_t ws_size,
                              hipStream_t stream) {
  const float* x         = (const float*)d_in[0];
  // d_in[1] = edge_index (unused; `neighbors` is its padded form)
  const int*   neighbors = (const int*)d_in[2];
  const float* templates = (const float*)d_in[3];
  const float* tfeat     = (const float*)d_in[4];
  const float* alpha     = (const float*)d_in[5];
  float* out = (float*)d_out;

  const int n_nodes = in_sizes[0] / FDIM;  // 15000
  fgw_kernel<<<n_nodes / 2, 256, 0, stream>>>(x, neighbors, templates, tfeat,
                                              alpha, out);
}

// Round 5
// 638.573 us; speedup vs baseline: 10.5423x; 1.5351x over previous
//
#include <hip/hip_runtime.h>

#define FDIM 16
#define TDIM 16
#define MDIM 10
#define KDIM 17
#define NCG 5

typedef float v2f __attribute__((ext_vector_type(2)));

// DPP quad_perm (pure VALU): xor1 = [1,0,3,2] = 0xB1, xor2 = [2,3,0,1] = 0x4E.
template <int CTRL>
__device__ __forceinline__ float dppf(float x) {
  return __int_as_float(__builtin_amdgcn_update_dpp(
      0, __float_as_int(x), CTRL, 0xF, 0xF, true));
}
// 4-lane (aligned quad) all-reduce, 2 stages, all-VALU.
__device__ __forceinline__ float rsum4(float v) {
  v += dppf<0xB1>(v);
  v += dppf<0x4E>(v);
  return v;
}
__device__ __forceinline__ float rmax4(float v) {
  v = fmaxf(v, dppf<0xB1>(v));
  v = fmaxf(v, dppf<0x4E>(v));
  return v;
}
__device__ __forceinline__ float bperm(int byte_addr, float x) {
  return __int_as_float(__builtin_amdgcn_ds_bpermute(byte_addr, __float_as_int(x)));
}

__global__ __launch_bounds__(128) void fgw_kernel(
    const float* __restrict__ x,        // [N,F]
    const int* __restrict__ nbrs,       // [N,K]
    const float* __restrict__ tmpl,     // [T,M,M]
    const float* __restrict__ tfeat,    // [T,M,F]
    const float* __restrict__ alpha,    // [1]
    float* __restrict__ out)            // [N,T]
{
  const int tid  = threadIdx.x;
  const int nl   = tid >> 6;          // node-local 0/1 (one wave per node)
  const int t    = (tid >> 2) & 15;   // template
  const int lane = tid & 3;           // quad lane: cols {lane, lane+4} + {8+lane if lane<2}
  const bool act2 = lane < 2;

  __shared__ int   sIdx[2 * KDIM];
  __shared__ float sN1[2 * KDIM];
  __shared__ v2f   sF1p[2][KDIM][FDIM];     // duplicated {v,v} for pk broadcast
  __shared__ float sM0w[2 * 16 * MDIM * 18]; // [nl][t][col][k], k-stride 18

  if (tid < 2 * KDIM)
    sIdx[tid] = nbrs[(blockIdx.x * 2 + tid / KDIM) * KDIM + tid % KDIM];
  __syncthreads();
  for (int i = tid; i < 2 * KDIM * FDIM; i += 128) {
    int nn = i / (KDIM * FDIM);
    int r  = i % (KDIM * FDIM);
    float val = x[sIdx[nn * KDIM + (r >> 4)] * FDIM + (r & 15)];
    v2f dup = {val, val};
    sF1p[nn][r >> 4][r & 15] = dup;
  }
  __syncthreads();
  if (tid < 2 * KDIM) {
    float s = 0.f;
#pragma unroll
    for (int f = 0; f < FDIM; ++f) {
      float vv = sF1p[tid / KDIM][tid % KDIM][f].x;
      s = fmaf(vv, vv, s);
    }
    sN1[tid] = s;
  }
  __syncthreads();

  const float a  = alpha[0];
  const float w0 = 1.f - a;
  const float w2 = 2.f * a;

  // template rows c0=lane, c1=lane+4 packed; c2=8+lane on lanes 0,1
  v2f c2rowP[MDIM]; float c2rowE[MDIM];
  v2f f2P[FDIM];    float f2E[FDIM];
#pragma unroll
  for (int j = 0; j < MDIM; ++j) {
    v2f tv = {tmpl[(t * MDIM + lane) * MDIM + j],
              tmpl[(t * MDIM + lane + 4) * MDIM + j]};
    c2rowP[j] = tv;
    c2rowE[j] = act2 ? tmpl[(t * MDIM + 8 + lane) * MDIM + j] : 0.f;
  }
#pragma unroll
  for (int f = 0; f < FDIM; ++f) {
    v2f tv = {tfeat[(t * MDIM + lane) * FDIM + f],
              tfeat[(t * MDIM + lane + 4) * FDIM + f]};
    f2P[f] = tv;
    f2E[f] = act2 ? tfeat[(t * MDIM + 8 + lane) * FDIM + f] : 0.f;
  }
  v2f n2P = {0.f, 0.f}; float n2E = 0.f;
#pragma unroll
  for (int f = 0; f < FDIM; ++f) { n2P = f2P[f] * f2P[f] + n2P; n2E = fmaf(f2E[f], f2E[f], n2E); }
  v2f c2cP = {0.f, 0.f}; float c2cE = 0.f;
#pragma unroll
  for (int j = 0; j < MDIM; ++j) { c2cP = c2rowP[j] * c2rowP[j] + c2cP; c2cE = fmaf(c2rowE[j], c2rowE[j], c2cE); }
  c2cP *= 0.1f; c2cE *= 0.1f;

  // column word offsets in sM0w
  const int base = (nl * 16 + t) * MDIM;
  const int cw0 = (base + lane) * 18;
  const int cw1 = (base + lane + 4) * 18;
  const int eoffc = act2 ? (8 + lane) : 9;       // clamped read col for dead lanes
  const int cwE = (base + eoffc) * 18;
  const int cwEw = (base + 8 + lane) * 18;       // write col (act2 only)

  // M0 = (1-a)*Mcost -> LDS; per-column stats in regs
  v2f M00P = {0.f, 0.f}, M0mxP = {-1e30f, -1e30f}, M0mnP = {1e30f, 1e30f};
  float M00E = 0.f, M0mxE = -1e30f, M0mnE = 1e30f;
  v2f ipm0P = {0.f, 0.f}; float ipm0E = 0.f;
#pragma unroll
  for (int k = 0; k < KDIM; ++k) {
    v2f dotP = {0.f, 0.f}; float dotE = 0.f;
#pragma unroll
    for (int f = 0; f < FDIM; ++f) {
      dotP = sF1p[nl][k][f] * f2P[f] + dotP;
      dotE = fmaf(sF1p[nl][k][f].x, f2E[f], dotE);
    }
    float n1 = sN1[nl * KDIM + k];
    v2f M0kP;
    M0kP.x = w0 * (n1 + n2P.x - 2.f * dotP.x);
    M0kP.y = w0 * (n1 + n2P.y - 2.f * dotP.y);
    float M0kE = w0 * (n1 + n2E - 2.f * dotE);
    sM0w[cw0 + k] = M0kP.x;
    sM0w[cw1 + k] = M0kP.y;
    if (act2) sM0w[cwEw + k] = M0kE;
    ipm0P += M0kP; ipm0E += M0kE;
    if (k == 0) { M00P = M0kP; M00E = M0kE; }
    else {
      M0mxP.x = fmaxf(M0mxP.x, M0kP.x); M0mnP.x = fminf(M0mnP.x, M0kP.x);
      M0mxP.y = fmaxf(M0mxP.y, M0kP.y); M0mnP.y = fminf(M0mnP.y, M0kP.y);
      M0mxE = fmaxf(M0mxE, M0kE); M0mnE = fminf(M0mnE, M0kE);
    }
  }
  __syncthreads();   // dead lanes read col 9 written by lane 1

  const float c1_0 = 16.f / 17.f;
  const float c1_r = 1.f / 17.f;
  const float CN  = -28.8539008178f;  // -log2(e)/eps
  const float L17 = 4.0874628413f;    // log2(17): folds h1 into K''

  // tracked functionals per column
  v2f t0P = {1.f / 170.f, 1.f / 170.f};
  v2f csP = {16.f / 170.f, 16.f / 170.f};
  v2f ipmP = ipm0P * (1.f / 170.f);
  float t0E = act2 ? 1.f / 170.f : 0.f;
  float csE = act2 ? 16.f / 170.f : 0.f;
  float ipmE = act2 ? ipm0E * (1.f / 170.f) : 0.f;

  int laneid = __builtin_amdgcn_mbcnt_hi(~0u, __builtin_amdgcn_mbcnt_lo(~0u, 0u));
  const int lbase = (laneid & 60) << 2;   // byte base of this quad

  v2f Kp[KDIM]; float KE[KDIM], u[KDIM];
  v2f vP, zsP; float vE, zsE;
  v2f d0P, d1P; float d0E, d1E;

  auto calc_d = [&]() {
    d0P = (v2f){0.f, 0.f}; d1P = (v2f){0.f, 0.f}; d0E = 0.f; d1E = 0.f;
#pragma unroll
    for (int j = 0; j < 4; ++j) {
      int ad = lbase | (j << 2);
      float cb = bperm(ad, csP.x), tb = bperm(ad, t0P.x);
      v2f cb2 = {cb, cb}, tb2 = {tb, tb};
      d0P = c2rowP[j] * cb2 + d0P;  d1P = c2rowP[j] * tb2 + d1P;
      d0E = fmaf(cb, c2rowE[j], d0E); d1E = fmaf(tb, c2rowE[j], d1E);
    }
#pragma unroll
    for (int j = 0; j < 4; ++j) {
      int ad = lbase | (j << 2);
      float cb = bperm(ad, csP.y), tb = bperm(ad, t0P.y);
      v2f cb2 = {cb, cb}, tb2 = {tb, tb};
      d0P = c2rowP[j + 4] * cb2 + d0P;  d1P = c2rowP[j + 4] * tb2 + d1P;
      d0E = fmaf(cb, c2rowE[j + 4], d0E); d1E = fmaf(tb, c2rowE[j + 4], d1E);
    }
#pragma unroll
    for (int j = 0; j < 2; ++j) {
      int ad = lbase | (j << 2);
      float cb = bperm(ad, csE), tb = bperm(ad, t0E);
      v2f cb2 = {cb, cb}, tb2 = {tb, tb};
      d0P = c2rowP[8 + j] * cb2 + d0P;  d1P = c2rowP[8 + j] * tb2 + d1P;
      d0E = fmaf(cb, c2rowE[8 + j], d0E); d1E = fmaf(tb, c2rowE[8 + j], d1E);
    }
  };

  auto ITER = [&](bool ren) {
    if (ren) {  // gauge renorm: exact cancellation by homogeneity
      float vm = rmax4(fmaxf(fmaxf(vP.x, vP.y), vE));
      float r = __builtin_amdgcn_rcpf(vm);
      vP *= (v2f){r, r}; vE *= r;
    }
    // u-phase: u_k = 1/(K''v) (h1-exact via L17 fold)
#pragma unroll
    for (int k = 0; k < KDIM; ++k) {
      v2f qp = Kp[k] * vP;
      float q = qp.x + qp.y;
      q = fmaf(KE[k], vE, q);
      u[k] = __builtin_amdgcn_rcpf(rsum4(q));
    }
    // z-phase: z_m = sum_k K''[k][m] u_k (split accumulators for ILP)
    v2f zA = {0.f, 0.f}, zB = {0.f, 0.f};
    float zEa = 0.f, zEb = 0.f;
#pragma unroll
    for (int k = 0; k < KDIM; k += 2) {
      v2f uk = {u[k], u[k]};
      zA = Kp[k] * uk + zA;
      zEa = fmaf(KE[k], u[k], zEa);
    }
#pragma unroll
    for (int k = 1; k < KDIM; k += 2) {
      v2f uk = {u[k], u[k]};
      zB = Kp[k] * uk + zB;
      zEb = fmaf(KE[k], u[k], zEb);
    }
    zsP = zA + zB; zsE = zEa + zEb;
    vP.x = 1.7f * __builtin_amdgcn_rcpf(zsP.x);   // 17*h2
    vP.y = 1.7f * __builtin_amdgcn_rcpf(zsP.y);
    vE = act2 ? 1.7f * __builtin_amdgcn_rcpf(zsE) : 0.f;
  };

#pragma unroll 1
  for (int it = 0; it < NCG; ++it) {
    calc_d();
    v2f c10v = {c1_0, c1_0}, c1rv = {c1_r, c1_r};
    v2f tens0P = c10v + c2cP - 2.f * d0P;
    v2f tens1P = c1rv + c2cP - 2.f * d1P;
    float tens0E = c1_0 + c2cE - 2.f * d0E;
    float tens1E = c1_r + c2cE - 2.f * d1E;

    // scale = max|G| (exact: G affine in M0 per row-class)
    float g0x = fmaf(w2, tens0P.x, M00P.x);
    float gax = fmaf(w2, tens1P.x, M0mxP.x);
    float gbx = fmaf(w2, tens1P.x, M0mnP.x);
    float mxx = fmaxf(fabsf(g0x), fmaxf(fabsf(gax), fabsf(gbx)));
    float g0y = fmaf(w2, tens0P.y, M00P.y);
    float gay = fmaf(w2, tens1P.y, M0mxP.y);
    float gby = fmaf(w2, tens1P.y, M0mnP.y);
    float mxy = fmaxf(fabsf(g0y), fmaxf(fabsf(gay), fabsf(gby)));
    float g0e = fmaf(w2, tens0E, M00E);
    float gae = fmaf(w2, tens1E, M0mxE);
    float gbe = fmaf(w2, tens1E, M0mnE);
    float mxe = fmaxf(fabsf(g0e), fmaxf(fabsf(gae), fabsf(gbe)));
    float mabs = rmax4(fmaxf(fmaxf(mxx, mxy), act2 ? mxe : 0.f));
    const float nsc = CN / (mabs + 1e-12f);

    // K'' build (exp2 natively; 51 exp2 per CG serve 16 pairs)
    const float nw2 = nsc * w2;
    float A0x = fmaf(nw2, tens0P.x, L17), A1x = fmaf(nw2, tens1P.x, L17);
    float A0y = fmaf(nw2, tens0P.y, L17), A1y = fmaf(nw2, tens1P.y, L17);
    float A0e = fmaf(nw2, tens0E, L17),  A1e = fmaf(nw2, tens1E, L17);
#pragma unroll
    for (int k = 0; k < KDIM; ++k) {
      float ax = fmaf(nsc, sM0w[cw0 + k], k ? A1x : A0x);
      float ay = fmaf(nsc, sM0w[cw1 + k], k ? A1y : A0y);
      float ae = fmaf(nsc, sM0w[cwE + k], k ? A1e : A0e);
      v2f kk = {__builtin_amdgcn_exp2f(ax), __builtin_amdgcn_exp2f(ay)};
      Kp[k] = kk;
      KE[k] = __builtin_amdgcn_exp2f(ae);
    }

    // 25 multiplicative Sinkhorn iterations; renorm every 2nd (range-safe)
    vP = (v2f){1.f, 1.f}; vE = act2 ? 1.f : 0.f;
    ITER(false); ITER(false);
#pragma unroll 1
    for (int sp = 0; sp < 11; ++sp) { ITER(true); ITER(false); }
    ITER(true);

    // CG update of (t0, cs, ipm) from S = u K'' v / 17
    v2f ipsP = {0.f, 0.f}; float ipsE = 0.f;
#pragma unroll
    for (int k = 0; k < KDIM; ++k) {
      v2f uk = {u[k], u[k]};
      v2f wk = Kp[k] * uk;
      v2f m2 = {sM0w[cw0 + k], sM0w[cw1 + k]};
      ipsP = wk * m2 + ipsP;
      ipsE = fmaf(KE[k] * u[k], sM0w[cwE + k], ipsE);
    }
    const float s17 = 1.f / 17.f;
    v2f s17v = {s17, s17};
    v2f colSP = vP * zsP * s17v;
    v2f u0v = {u[0], u[0]};
    v2f t0SP = u0v * Kp[0] * vP * s17v;
    v2f csSP = colSP - t0SP;
    v2f ipSP = ipsP * vP * s17v;
    float colSE = vE * zsE * s17;
    float t0SE  = u[0] * KE[0] * vE * s17;
    float csSE  = colSE - t0SE;
    float ipSE  = ipsE * vE * s17;

    const float gamma = 2.f / (float)(it + 2);
    const float om = 1.f - gamma;
    t0P = om * t0P + gamma * t0SP;  csP = om * csP + gamma * csSP;  ipmP = om * ipmP + gamma * ipSP;
    t0E = om * t0E + gamma * t0SE;  csE = om * csE + gamma * csSE;  ipmE = om * ipmE + gamma * ipSE;
  }

  // final: fgw = <T,M0> + a*<tens(T),T> via (t0, cs) functionals
  calc_d();
  v2f c10v = {c1_0, c1_0}, c1rv = {c1_r, c1_r};
  v2f tens0P = c10v + c2cP - 2.f * d0P;
  v2f tens1P = c1rv + c2cP - 2.f * d1P;
  float tens0E = c1_0 + c2cE - 2.f * d0E;
  float tens1E = c1_r + c2cE - 2.f * d1E;

  v2f accP = ipmP + a * (tens0P * t0P + tens1P * csP);
  float accE = ipmE + a * (tens0E * t0E + tens1E * csE);
  float acc = accP.x + accP.y + accE;
  acc = rsum4(acc);
  if (lane == 0) out[(blockIdx.x * 2 + nl) * TDIM + t] = acc;
}

extern "C" void kernel_launch(void* const* d_in, const int* in_sizes, int n_in,
                              void* d_out, int out_size, void* d_ws, size_t ws_size,
                              hipStream_t stream) {
  const float* x         = (const float*)d_in[0];
  // d_in[1] = edge_index (unused; `neighbors` is its padded form)
  const int*   neighbors = (const int*)d_in[2];
  const float* templates = (const float*)d_in[3];
  const float* tfeat     = (const float*)d_in[4];
  const float* alpha     = (const float*)d_in[5];
  float* out = (float*)d_out;

  const int n_nodes = in_sizes[0] / FDIM;  // 15000
  fgw_kernel<<<n_nodes / 2, 128, 0, stream>>>(x, neighbors, templates, tfeat,
                                              alpha, out);
}

// Round 6
// 441.362 us; speedup vs baseline: 15.2529x; 1.4468x over previous
//
#include <hip/hip_runtime.h>

#define MDIM 10
#define KDIM 17
#define NCG 5

typedef float v2f __attribute__((ext_vector_type(2)));
typedef float v4f __attribute__((ext_vector_type(4)));

// DPP quad_perm xor1 = [1,0,3,2] = 0xB1 : swap within 2-lane pair (pure VALU).
template <int CTRL>
__device__ __forceinline__ float dppf(float x) {
  return __int_as_float(__builtin_amdgcn_update_dpp(
      0, __float_as_int(x), CTRL, 0xF, 0xF, true));
}
__device__ __forceinline__ float other1(float v) { return dppf<0xB1>(v); }
__device__ __forceinline__ v2f vmax2(v2f a, v2f b) {
  v2f r; r.x = fmaxf(a.x, b.x); r.y = fmaxf(a.y, b.y); return r;
}
__device__ __forceinline__ v2f vmin2(v2f a, v2f b) {
  v2f r; r.x = fminf(a.x, b.x); r.y = fminf(a.y, b.y); return r;
}

__global__ __launch_bounds__(64) void fgw_kernel(
    const float* __restrict__ x,        // [N,16]
    const int* __restrict__ nbrs,       // [N,17]
    const float* __restrict__ tmpl,     // [16,10,10]
    const float* __restrict__ tfeat,    // [16,10,16]
    const float* __restrict__ alpha,    // [1]
    float* __restrict__ out)            // [N,16]
{
  const int tid  = threadIdx.x;
  const int lane = tid & 1;           // 2-lane group; owned cols = lane + 2s, s=0..4
  const int t    = (tid >> 1) & 15;   // template
  const int nl   = tid >> 5;          // node-local 0/1
  const int node = blockIdx.x * 2 + nl;

  // per-lane private scratch: [nl][t][col][k], col = lane+2s -> base + 34*s + k
  __shared__ float sM0[2 * 16 * MDIM * KDIM];
  float* p = &sM0[((nl * 16 + t) * MDIM + lane) * KDIM];

  const float a  = alpha[0];
  const float w0 = 1.f - a;
  const float w2 = 2.f * a;

  const float* tm = tmpl  + (size_t)t * MDIM * MDIM;
  const float* tf = tfeat + (size_t)t * MDIM * 16;

  // ---- template features for owned cols (transient regs, dead after M0 build)
  v2f f2A[16], f2B[16]; float f2E[16];
#pragma unroll
  for (int f = 0; f < 16; ++f) {
    f2A[f] = (v2f){tf[lane * 16 + f],       tf[(lane + 2) * 16 + f]};
    f2B[f] = (v2f){tf[(lane + 4) * 16 + f], tf[(lane + 6) * 16 + f]};
    f2E[f] = tf[(lane + 8) * 16 + f];
  }
  v2f n2A = {0.f, 0.f}, n2B = {0.f, 0.f}; float n2E = 0.f;
#pragma unroll
  for (int f = 0; f < 16; ++f) {
    n2A = f2A[f] * f2A[f] + n2A;
    n2B = f2B[f] * f2B[f] + n2B;
    n2E = fmaf(f2E[f], f2E[f], n2E);
  }
  // (C2*C2)@h2 per owned col
  v2f c2cA = {0.f, 0.f}, c2cB = {0.f, 0.f}; float c2cE = 0.f;
#pragma unroll
  for (int j = 0; j < MDIM; ++j) {
    v2f cA = {tm[lane * MDIM + j],       tm[(lane + 2) * MDIM + j]};
    v2f cB = {tm[(lane + 4) * MDIM + j], tm[(lane + 6) * MDIM + j]};
    float cE = tm[(lane + 8) * MDIM + j];
    c2cA = cA * cA + c2cA; c2cB = cB * cB + c2cB; c2cE = fmaf(cE, cE, c2cE);
  }
  c2cA *= 0.1f; c2cB *= 0.1f; c2cE *= 0.1f;

  // ---- M0 = (1-a)*Mcost -> LDS scratch; per-column stats in regs
  v2f M00A = {0.f, 0.f}, M00B = {0.f, 0.f}; float M00E = 0.f;
  v2f mxA = {-1e30f, -1e30f}, mxB = {-1e30f, -1e30f}; float mxE = -1e30f;
  v2f mnA = {1e30f, 1e30f},  mnB = {1e30f, 1e30f};  float mnE = 1e30f;
  v2f ip0A = {0.f, 0.f}, ip0B = {0.f, 0.f}; float ip0E = 0.f;
#pragma unroll
  for (int k = 0; k < KDIM; ++k) {
    int idx = nbrs[node * KDIM + k];
    const v4f* xr = (const v4f*)(x + (size_t)idx * 16);
    v4f r0 = xr[0], r1 = xr[1], r2 = xr[2], r3 = xr[3];
    float n1 = 0.f; v2f dA = {0.f, 0.f}, dB = {0.f, 0.f}; float dE = 0.f;
#pragma unroll
    for (int f = 0; f < 16; ++f) {
      float vv = (f < 4) ? r0[f & 3] : (f < 8) ? r1[f & 3] : (f < 12) ? r2[f & 3] : r3[f & 3];
      n1 = fmaf(vv, vv, n1);
      v2f vv2 = {vv, vv};
      dA = f2A[f] * vv2 + dA;
      dB = f2B[f] * vv2 + dB;
      dE = fmaf(f2E[f], vv, dE);
    }
    v2f n1v = {n1, n1};
    v2f MA = (n1v + n2A - 2.f * dA) * w0;
    v2f MB = (n1v + n2B - 2.f * dB) * w0;
    float ME = w0 * (n1 + n2E - 2.f * dE);
    p[k] = MA.x; p[34 + k] = MA.y; p[68 + k] = MB.x; p[102 + k] = MB.y; p[136 + k] = ME;
    ip0A += MA; ip0B += MB; ip0E += ME;
    if (k == 0) { M00A = MA; M00B = MB; M00E = ME; }
    else {
      mxA = vmax2(mxA, MA); mnA = vmin2(mnA, MA);
      mxB = vmax2(mxB, MB); mnB = vmin2(mnB, MB);
      mxE = fmaxf(mxE, ME); mnE = fminf(mnE, ME);
    }
  }

  const float c1_0 = 16.f / 17.f;     // (C1@h1)[0]
  const float c1_r = 1.f / 17.f;      // (C1@h1)[k>=1]
  const float CN  = -28.8539008178f;  // -log2(e)/eps, eps = 0.05
  const float L17 = 4.0874628413f;    // log2(17): folds h1 into K''

  // tracked functionals per owned col
  v2f t0A = {1.f/170.f, 1.f/170.f}, t0B = {1.f/170.f, 1.f/170.f}; float t0E = 1.f/170.f;
  v2f csA = {16.f/170.f, 16.f/170.f}, csB = {16.f/170.f, 16.f/170.f}; float csE = 16.f/170.f;
  v2f ipmA = ip0A * (1.f/170.f), ipmB = ip0B * (1.f/170.f); float ipmE = ip0E * (1.f/170.f);

  v2f KA[KDIM], KB[KDIM]; float KE[KDIM];
  float u[KDIM];
  v2f vA, vB, zA, zB; float vE, zE;
  v2f d0A, d0B, d1A, d1B; float d0E, d1E;

  auto calc_d = [&]() {
    // gather all 10 (cs, t0) values: per slot, partner via 1 DPP + 2 selects
    float csv[MDIM], t0v[MDIM];
    {
      float s0 = csA.x, s1 = csA.y, s2 = csB.x, s3 = csB.y, s4 = csE;
      float o0 = other1(s0), o1 = other1(s1), o2 = other1(s2), o3 = other1(s3), o4 = other1(s4);
      csv[0] = lane ? o0 : s0; csv[1] = lane ? s0 : o0;
      csv[2] = lane ? o1 : s1; csv[3] = lane ? s1 : o1;
      csv[4] = lane ? o2 : s2; csv[5] = lane ? s2 : o2;
      csv[6] = lane ? o3 : s3; csv[7] = lane ? s3 : o3;
      csv[8] = lane ? o4 : s4; csv[9] = lane ? s4 : o4;
    }
    {
      float s0 = t0A.x, s1 = t0A.y, s2 = t0B.x, s3 = t0B.y, s4 = t0E;
      float o0 = other1(s0), o1 = other1(s1), o2 = other1(s2), o3 = other1(s3), o4 = other1(s4);
      t0v[0] = lane ? o0 : s0; t0v[1] = lane ? s0 : o0;
      t0v[2] = lane ? o1 : s1; t0v[3] = lane ? s1 : o1;
      t0v[4] = lane ? o2 : s2; t0v[5] = lane ? s2 : o2;
      t0v[6] = lane ? o3 : s3; t0v[7] = lane ? s3 : o3;
      t0v[8] = lane ? o4 : s4; t0v[9] = lane ? s4 : o4;
    }
    d0A = (v2f){0.f, 0.f}; d0B = (v2f){0.f, 0.f}; d0E = 0.f;
    d1A = (v2f){0.f, 0.f}; d1B = (v2f){0.f, 0.f}; d1E = 0.f;
#pragma unroll
    for (int j = 0; j < MDIM; ++j) {
      v2f cA = {tm[lane * MDIM + j],       tm[(lane + 2) * MDIM + j]};
      v2f cB = {tm[(lane + 4) * MDIM + j], tm[(lane + 6) * MDIM + j]};
      float cE = tm[(lane + 8) * MDIM + j];
      v2f cj = {csv[j], csv[j]}, tj = {t0v[j], t0v[j]};
      d0A = cA * cj + d0A; d0B = cB * cj + d0B; d0E = fmaf(cE, csv[j], d0E);
      d1A = cA * tj + d1A; d1B = cB * tj + d1B; d1E = fmaf(cE, t0v[j], d1E);
    }
  };

  auto ITER = [&](bool ren) {
    if (ren) {  // gauge renorm: exact cancellation by homogeneity
      float vm = fmaxf(fmaxf(fmaxf(vA.x, vA.y), fmaxf(vB.x, vB.y)), vE);
      vm = fmaxf(vm, other1(vm));
      float r = __builtin_amdgcn_rcpf(vm);
      vA *= r; vB *= r; vE *= r;
    }
    // u-phase: u_k = 1/(K''v) (h1-exact via L17 fold); 1 DPP stage
#pragma unroll
    for (int k = 0; k < KDIM; ++k) {
      v2f q = KA[k] * vA;
      q = KB[k] * vB + q;
      float h = q.x + q.y;
      h = fmaf(KE[k], vE, h);
      h += other1(h);
      u[k] = __builtin_amdgcn_rcpf(h);
    }
    // z-phase: z_m = sum_k K''[k][m] u_k (split accumulators for ILP)
    v2f zA0 = {0.f, 0.f}, zA1 = {0.f, 0.f}, zB0 = {0.f, 0.f}, zB1 = {0.f, 0.f};
    float zE0 = 0.f, zE1 = 0.f;
#pragma unroll
    for (int k = 0; k < KDIM; k += 2) {
      v2f uk = {u[k], u[k]};
      zA0 = KA[k] * uk + zA0; zB0 = KB[k] * uk + zB0; zE0 = fmaf(KE[k], u[k], zE0);
    }
#pragma unroll
    for (int k = 1; k < KDIM; k += 2) {
      v2f uk = {u[k], u[k]};
      zA1 = KA[k] * uk + zA1; zB1 = KB[k] * uk + zB1; zE1 = fmaf(KE[k], u[k], zE1);
    }
    zA = zA0 + zA1; zB = zB0 + zB1; zE = zE0 + zE1;
    vA.x = 1.7f * __builtin_amdgcn_rcpf(zA.x);   // 17*h2
    vA.y = 1.7f * __builtin_amdgcn_rcpf(zA.y);
    vB.x = 1.7f * __builtin_amdgcn_rcpf(zB.x);
    vB.y = 1.7f * __builtin_amdgcn_rcpf(zB.y);
    vE   = 1.7f * __builtin_amdgcn_rcpf(zE);
  };

#pragma unroll 1
  for (int it = 0; it < NCG; ++it) {
    calc_d();
    v2f tens0A = c1_0 + c2cA - 2.f * d0A;
    v2f tens1A = c1_r + c2cA - 2.f * d1A;
    v2f tens0B = c1_0 + c2cB - 2.f * d0B;
    v2f tens1B = c1_r + c2cB - 2.f * d1B;
    float tens0E = c1_0 + c2cE - 2.f * d0E;
    float tens1E = c1_r + c2cE - 2.f * d1E;

    // scale = max|G| (exact: G affine in M0 per row-class)
    v2f g0A = w2 * tens0A + M00A, gaA = w2 * tens1A + mxA, gbA = w2 * tens1A + mnA;
    v2f g0B = w2 * tens0B + M00B, gaB = w2 * tens1B + mxB, gbB = w2 * tens1B + mnB;
    float g0E = fmaf(w2, tens0E, M00E), gaE = fmaf(w2, tens1E, mxE), gbE = fmaf(w2, tens1E, mnE);
    float m0 = fmaxf(fmaxf(fabsf(g0A.x), fabsf(g0A.y)), fmaxf(fabsf(g0B.x), fabsf(g0B.y)));
    float m1 = fmaxf(fmaxf(fabsf(gaA.x), fabsf(gaA.y)), fmaxf(fabsf(gaB.x), fabsf(gaB.y)));
    float m2 = fmaxf(fmaxf(fabsf(gbA.x), fabsf(gbA.y)), fmaxf(fabsf(gbB.x), fabsf(gbB.y)));
    float m3 = fmaxf(fabsf(g0E), fmaxf(fabsf(gaE), fabsf(gbE)));
    float mabs = fmaxf(fmaxf(m0, m1), fmaxf(m2, m3));
    mabs = fmaxf(mabs, other1(mabs));
    const float nsc = CN * __builtin_amdgcn_rcpf(mabs + 1e-12f);

    // K'' build: 85 exp2 per CG serve 32 pairs
    const float nw2 = nsc * w2;
    v2f A0A = nw2 * tens0A + L17, A1A = nw2 * tens1A + L17;
    v2f A0B = nw2 * tens0B + L17, A1B = nw2 * tens1B + L17;
    float A0E = fmaf(nw2, tens0E, L17), A1E = fmaf(nw2, tens1E, L17);
    v2f nscv = {nsc, nsc};
#pragma unroll
    for (int k = 0; k < KDIM; ++k) {
      v2f mA = {p[k], p[34 + k]};
      v2f mB = {p[68 + k], p[102 + k]};
      v2f argA = nscv * mA + (k ? A1A : A0A);
      v2f argB = nscv * mB + (k ? A1B : A0B);
      KA[k] = (v2f){__builtin_amdgcn_exp2f(argA.x), __builtin_amdgcn_exp2f(argA.y)};
      KB[k] = (v2f){__builtin_amdgcn_exp2f(argB.x), __builtin_amdgcn_exp2f(argB.y)};
      KE[k] = __builtin_amdgcn_exp2f(fmaf(nsc, p[136 + k], k ? A1E : A0E));
    }

    // 25 multiplicative Sinkhorn iterations; renorm every 2nd (range-safe)
    vA = (v2f){1.f, 1.f}; vB = (v2f){1.f, 1.f}; vE = 1.f;
    ITER(false); ITER(false);
#pragma unroll 1
    for (int sp = 0; sp < 11; ++sp) { ITER(true); ITER(false); }
    ITER(true);

    // CG update of (t0, cs, ipm) from S = u K'' v / 17
    v2f ipsA = {0.f, 0.f}, ipsB = {0.f, 0.f}; float ipsE = 0.f;
#pragma unroll
    for (int k = 0; k < KDIM; ++k) {
      v2f uk = {u[k], u[k]};
      v2f mA = {p[k], p[34 + k]};
      v2f mB = {p[68 + k], p[102 + k]};
      ipsA = (KA[k] * uk) * mA + ipsA;
      ipsB = (KB[k] * uk) * mB + ipsB;
      ipsE = fmaf(KE[k] * u[k], p[136 + k], ipsE);
    }
    const float s17 = 1.f / 17.f;
    v2f u0s = {u[0] * s17, u[0] * s17};
    v2f colSA = vA * zA * s17,  colSB = vB * zB * s17;
    v2f t0SA = (KA[0] * vA) * u0s, t0SB = (KB[0] * vB) * u0s;
    v2f csSA = colSA - t0SA, csSB = colSB - t0SB;
    v2f ipSA = ipsA * vA * s17, ipSB = ipsB * vB * s17;
    float colSE = vE * zE * s17;
    float t0SE  = KE[0] * vE * u[0] * s17;
    float csSE  = colSE - t0SE;
    float ipSE  = ipsE * vE * s17;

    const float gamma = 2.f / (float)(it + 2);
    const float om = 1.f - gamma;
    t0A = om * t0A + gamma * t0SA;  t0B = om * t0B + gamma * t0SB;  t0E = om * t0E + gamma * t0SE;
    csA = om * csA + gamma * csSA;  csB = om * csB + gamma * csSB;  csE = om * csE + gamma * csSE;
    ipmA = om * ipmA + gamma * ipSA; ipmB = om * ipmB + gamma * ipSB; ipmE = om * ipmE + gamma * ipSE;
  }

  // final: fgw = <T,M0> + a*<tens(T),T> via (t0, cs) functionals
  calc_d();
  v2f tens0A = c1_0 + c2cA - 2.f * d0A;
  v2f tens1A = c1_r + c2cA - 2.f * d1A;
  v2f tens0B = c1_0 + c2cB - 2.f * d0B;
  v2f tens1B = c1_r + c2cB - 2.f * d1B;
  float tens0E = c1_0 + c2cE - 2.f * d0E;
  float tens1E = c1_r + c2cE - 2.f * d1E;

  v2f accA = ipmA + a * (tens0A * t0A + tens1A * csA);
  v2f accB = ipmB + a * (tens0B * t0B + tens1B * csB);
  float accE = ipmE + a * (tens0E * t0E + tens1E * csE);
  float acc = accA.x + accA.y + accB.x + accB.y + accE;
  acc += other1(acc);
  if (lane == 0) out[node * 16 + t] = acc;
}

extern "C" void kernel_launch(void* const* d_in, const int* in_sizes, int n_in,
                              void* d_out, int out_size, void* d_ws, size_t ws_size,
                              hipStream_t stream) {
  const float* x         = (const float*)d_in[0];
  // d_in[1] = edge_index (unused; `neighbors` is its padded form)
  const int*   neighbors = (const int*)d_in[2];
  const float* templates = (const float*)d_in[3];
  const float* tfeat     = (const float*)d_in[4];
  const float* alpha     = (const float*)d_in[5];
  float* out = (float*)d_out;

  const int n_nodes = in_sizes[0] / 16;  // 15000
  fgw_kernel<<<n_nodes / 2, 64, 0, stream>>>(x, neighbors, templates, tfeat,
                                             alpha, out);
}